// Round 1
// 1440.169 us; speedup vs baseline: 1.1680x; 1.1680x over previous
//
#include <hip/hip_runtime.h>
#include <math.h>

#define TT 96
#define BB 128
#define DD 800
#define LL 128

typedef _Float16 h2v __attribute__((ext_vector_type(2)));
typedef _Float16 f16x8 __attribute__((ext_vector_type(8)));
typedef float f32x4 __attribute__((ext_vector_type(4)));

// ---- ws layout (4B units), shared host/device ----
constexpr size_t O_WPX  = 0;                      // 102400 fp32
constexpr size_t O_WPR  = O_WPX  + 102400;        // 16384 uints (fdot2 pack)
constexpr size_t O_WEN  = O_WPR  + 16384;         // 32768
constexpr size_t O_WPZ  = O_WEN  + 32768;         // 8192 (fdot2 pack, phase2)
constexpr size_t O_WIHX = O_WPZ  + 8192;          // 32768
constexpr size_t O_BFIZ = O_WIHX + 32768;         // 32768 (MFMA B-frags W_ihz^T)
constexpr size_t O_BFHH = O_BFIZ + 32768;         // 32768 (MFMA B-frags W_hh^T)
constexpr size_t O_WDEZ = O_BFHH + 32768;         // 51200
constexpr size_t O_WDEO = O_WDEZ + 51200;         // 51200
constexpr size_t O_BL   = O_WDEO + 51200;         // 512
constexpr size_t O_ACC  = O_BL   + 512;           // 2 (double)
constexpr size_t O_XHAT = O_ACC  + 4;             // 786432 uints used
constexpr size_t O_BFPZ = O_XHAT + 786432;        // 8192 (MFMA B-frags W_pz^T)
constexpr size_t O_PROG = O_XHAT + 800000;        // 128 ints (progress flags, in XHAT gap)
constexpr size_t O_OUT  = O_XHAT + 1572864;
constexpr size_t O_MUQ  = O_OUT  + 1572864;
constexpr size_t O_SGQ  = O_MUQ  + 1572864;
constexpr size_t O_MUP  = O_SGQ  + 1572864;
constexpr size_t O_SGP  = O_MUP  + 1572864;

__device__ __forceinline__ h2v u2h(unsigned u) {
  union { unsigned u; h2v h; } x; x.u = u; return x.h;
}
__device__ __forceinline__ float fdot2(unsigned w, unsigned v, float acc) {
  return __builtin_amdgcn_fdot2(u2h(w), u2h(v), acc, false);
}
__device__ __forceinline__ unsigned packf16(float a, float b) {
  union { _Float16 h[2]; unsigned u; } x;
  x.h[0] = (_Float16)a; x.h[1] = (_Float16)b;
  return x.u;
}
__device__ __forceinline__ f16x8 u4h8(uint4 u) {
  union { uint4 u; f16x8 h; } x; x.u = u; return x.h;
}
__device__ __forceinline__ f32x4 mfma16(uint4 a, uint4 b, f32x4 c) {
  return __builtin_amdgcn_mfma_f32_16x16x32_f16(u4h8(a), u4h8(b), c, 0, 0, 0);
}
__device__ __forceinline__ float sigm(float x) { return 1.f/(1.f + __expf(-x)); }
__device__ __forceinline__ float hsum4(float4 a) { return (a.x + a.y) + (a.z + a.w); }

__device__ __forceinline__ void dotacc4(uint4 wv, uint4 vv, float4& av) {
  av.x = fdot2(wv.x, vv.x, av.x);
  av.y = fdot2(wv.y, vv.y, av.y);
  av.z = fdot2(wv.z, vv.z, av.z);
  av.w = fdot2(wv.w, vv.w, av.w);
}

// device-visible (agent-scope, sc1) stores/loads for cross-XCD producer->consumer handoff
__device__ __forceinline__ void gstore(float* p, float v) {
  __hip_atomic_store(p, v, __ATOMIC_RELAXED, __HIP_MEMORY_SCOPE_AGENT);
}
__device__ __forceinline__ float gload(const float* p) {
  return __hip_atomic_load(p, __ATOMIC_RELAXED, __HIP_MEMORY_SCOPE_AGENT);
}

// ---------------- prep ----------------
__global__ void prep_misc(const float* __restrict__ b_ih, const float* __restrict__ b_hh,
                          float* __restrict__ b_lstm, double* __restrict__ accum,
                          int* __restrict__ prog) {
  int t = threadIdx.x;
  if (t < 512) b_lstm[t] = b_ih[t] + b_hh[t];
  if (t == 0) accum[0] = 0.0;
  // sc1 store so a later sc1 (IC-direct) consumer load can never see a stale
  // flag from the previous graph replay.
  if (t < 128) __hip_atomic_store(&prog[t], 0, __ATOMIC_RELAXED, __HIP_MEMORY_SCOPE_AGENT);
}

// f16 interleaved pack (fdot2 layout)
__global__ void prep_pack_f16(const float* __restrict__ src, unsigned* __restrict__ dst,
                              int J, int rs, int k0, int total) {
  int idx = blockIdx.x * 256 + threadIdx.x;
  if (idx >= total) return;
  int u = idx & 3;
  int t2 = idx >> 2;
  int k8 = t2 / J;
  int j = t2 - k8 * J;
  int k = k8 * 8 + u * 2;
  const float* r = src + (size_t)j * rs + k0 + k;
  dst[idx] = packf16(r[0], r[1]);
}

// MFMA B-fragment layout pack (see earlier session notes)
__global__ void prep_bfrag(const float* __restrict__ src, unsigned* __restrict__ dst,
                           int rs, int k0, int KS, int mode, int total) {
  int idx = blockIdx.x * 256 + threadIdx.x;
  if (idx >= total) return;
  int jj = idx & 3;
  int lane = (idx >> 2) & 63;
  int t2 = idx >> 8;
  int ks = t2 % KS;
  int g = t2 / KS;
  int n = (mode == 0) ? (128 * (g & 3) + 16 * (g >> 2) + (lane & 15))
                      : (16 * g + (lane & 15));
  int k = ks * 32 + (lane >> 4) * 8 + jj * 2;
  const float* r = src + (size_t)n * rs + k0 + k;
  dst[idx] = packf16(r[0], r[1]);
}

// fp32 interleaved transpose (for W_px)
__global__ void prep_transpose(const float* __restrict__ src, float* __restrict__ dst,
                               int J, int rs, int k0, int total) {
  int idx = blockIdx.x * 256 + threadIdx.x;
  if (idx >= total) return;
  int J4 = J * 4;
  int k4 = idx / J4;
  int rem = idx - k4 * J4;
  int j = rem >> 2;
  int kk = rem & 3;
  dst[idx] = src[j * rs + k0 + k4 * 4 + kk];
}

// ---------------- phase 0: x_hat (emits f16-packed pairs) ----------------
__device__ __forceinline__ float dot4(float4 w, float4 v) {
  return w.x*v.x + w.y*v.y + w.z*v.z + w.w*v.w;
}
__global__ __launch_bounds__(256) void xhat_kernel(const float* __restrict__ x,
                                                   const float* __restrict__ Wpx4,
                                                   const float* __restrict__ b_px,
                                                   unsigned* __restrict__ xhat2) {
  __shared__ __align__(16) float sx[8][800];
  const int wg = blockIdx.x, tid = threadIdx.x;
  const int p0 = wg * 8;
  for (int r = 0; r < 8; ++r) {
    int p = p0 + r; int t = p >> 7; int b = p & 127;
    const float* row = x + ((size_t)b * TT + t) * 800;
    for (int col = tid; col < 800; col += 256) sx[r][col] = row[col];
  }
  __syncthreads();
  const int j = tid & 127, g = tid >> 7;
  float acc[4];
  const float bj = b_px[j];
  #pragma unroll
  for (int u = 0; u < 4; ++u) acc[u] = bj;
  const float4* W = (const float4*)Wpx4;
  #pragma unroll 2
  for (int k4 = 0; k4 < 200; ++k4) {
    float4 w = W[k4 * 128 + j];
    #pragma unroll
    for (int u = 0; u < 4; ++u) {
      float4 xv = *(const float4*)&sx[g + 2*u][k4 * 4];
      acc[u] += dot4(w, xv);
    }
  }
  #pragma unroll
  for (int u = 0; u < 4; ++u) {
    float v = fmaxf(acc[u], 0.f);
    float vp = __shfl_xor(v, 1, 64);
    if ((j & 1) == 0) {
      int p = p0 + g + 2*u;
      xhat2[(size_t)p * 64 + (j >> 1)] = packf16(v, vp);
    }
  }
}

// ---------------- fused producer/consumer kernel ----------------
// Blocks [0,128): phase1 producer, one batch chain each (body identical to the
//   previous phase1_kernel except the five g_* stores are agent-scope (sc1)
//   and a per-b progress flag is published after B3 (B3's pre-barrier
//   vmcnt(0) drains all of timestep t's data stores first).
// Blocks [128,256): phase2 consumers. 24 chunks each (chunk = 4 (t,b) pairs),
//   t-interleaved so each consumer's next chunk is ~4 timesteps ahead of its
//   last. Spin (s_sleep) on the 4 flags, then run the 512-thread-adapted
//   phase2 body. Capacity ~350-530us of issue work inside a 1117us window.
// Cooperative launch guarantees all 256 blocks co-resident (1 block/CU:
// 64KB LDS total, <=256 VGPR) so the spin cannot deadlock.
__global__ __launch_bounds__(512) void fused_kernel(
    const float* __restrict__ eps, const unsigned* __restrict__ xhat2g,
    const uint4* __restrict__ Wpr4, const float* __restrict__ b_pr,
    const uint4* __restrict__ Wen4, const float* __restrict__ b_en,
    const uint4* __restrict__ BFpz, const float* __restrict__ b_pz,
    const uint4* __restrict__ Wihx4, const uint4* __restrict__ BFihz,
    const uint4* __restrict__ BFhh, const float* __restrict__ b_lstm,
    float* __restrict__ g_out, float* __restrict__ g_muq, float* __restrict__ g_sgq,
    float* __restrict__ g_mup, float* __restrict__ g_sgp,
    const float* __restrict__ x, const float* __restrict__ beta_p,
    const uint4* __restrict__ Wpz4,
    const uint4* __restrict__ Wdez4, const uint4* __restrict__ Wdeo4,
    const float* __restrict__ b_de,
    double* __restrict__ accum, int* __restrict__ prog)
{
  const int tid = threadIdx.x;

  if (blockIdx.x < 128) {
    // ================= producer: phase1 =================
    __shared__ __align__(16) float s_gz[5120];        // [10][512] gate pre-acts
    __shared__ __align__(16) _Float16 s_z2[16*136];   // padded rows (stride 136)
    __shared__ __align__(16) _Float16 s_zh2[16*136];
    __shared__ __align__(16) float s_gxh[512];
    __shared__ __align__(16) float s_out[128];
    __shared__ __align__(16) float s_ehmu[128];
    __shared__ __align__(16) float s_mup[128];
    __shared__ __align__(16) float s_sgp[128];
    __shared__ __align__(16) float s_sgq[128];
    __shared__ __align__(16) unsigned s_out2[64];
    __shared__ __align__(16) unsigned s_xh2[64];
    __shared__ __align__(16) _Float16 s_h2[128];

    const int b = blockIdx.x;
    const int wv = tid >> 6;
    const int lane = tid & 63;
    const int l15 = lane & 15;
    const int quad = lane >> 4;

    if (tid < 128) { s_out[tid] = 0.f; s_h2[tid] = (_Float16)0.f; }
    float c_reg = 0.f;                       // lanes<16: cell state for h-idx 16*wv+lane
    const float blst = b_lstm[tid];
    const float bias_pe = (tid < 256) ? b_pr[tid] : b_en[tid - 256];
    const float bz = b_pz[16 * wv + l15];

    for (int t = 0; t < TT; ++t) {
      const size_t pb = (size_t)t * BB + b;
      const float* epsb = eps + pb * 1280;
      unsigned xh_pref = 0;
      if (tid >= 192 && tid < 256) xh_pref = xhat2g[pb * 64 + (tid - 192)];
      float e0 = epsb[tid];
      float e1 = epsb[tid + 512];
      float e2 = (tid < 256) ? epsb[tid + 1024] : 0.f;

      __syncthreads();                       // B0: prev s_out/s_h2 visible
      float oacc = 0.f;
      if (tid < 128) {
        gstore(&g_out[pb * 128 + tid], s_out[tid]);
      } else if (tid < 192) {
        int m = tid - 128;
        s_out2[m] = packf16(s_out[2*m], s_out[2*m + 1]);
      } else if (tid < 256) {
        s_xh2[tid - 192] = xh_pref;
      }
      __syncthreads();                       // B1

      // prior (tid<256) / encoder (tid>=256): fdot2, weights streamed from L2
      {
        float4 a4 = {bias_pe, 0.f, 0.f, 0.f};
        if (tid < 256) {
          #pragma unroll 4
          for (int k8 = 0; k8 < 16; ++k8) {
            uint4 w = Wpr4[k8 * 256 + tid];
            uint4 o = *(const uint4*)&s_out2[k8 * 4];
            dotacc4(w, o, a4);
          }
          float ph = fmaxf(hsum4(a4), 0.f);
          if (tid < 128) { s_mup[tid] = ph; gstore(&g_mup[pb * 128 + tid], ph); }
          else {
            float y = expf(ph) + 0.5f;
            float sp = (y > 20.f) ? y : log1pf(expf(y));
            s_sgp[tid - 128] = sp; gstore(&g_sgp[pb * 128 + tid - 128], sp);
          }
        } else {
          int j2 = tid - 256;
          #pragma unroll 4
          for (int k8 = 0; k8 < 16; ++k8) {
            uint4 w = Wen4[k8 * 256 + j2];
            uint4 o = *(const uint4*)&s_out2[k8 * 4];
            dotacc4(w, o, a4);
          }
          #pragma unroll 4
          for (int k8 = 16; k8 < 32; ++k8) {
            uint4 w = Wen4[k8 * 256 + j2];
            uint4 o = *(const uint4*)&s_xh2[(k8 - 16) * 4];
            dotacc4(w, o, a4);
          }
          float eh = fmaxf(hsum4(a4), 0.f);
          if (j2 < 128) s_ehmu[j2] = eh;
          else { float sq = expf(eh); s_sgq[j2 - 128] = sq; gstore(&g_sgq[pb * 128 + j2 - 128], sq); }
        }
      }
      __syncthreads();                       // B2

      // z into padded s_z2 rows (sample = row)
      {
        int l = tid & 127, s0 = tid >> 7;
        float mu = s_ehmu[l] + s_mup[l];
        float sq = s_sgq[l];
        s_z2[s0 * 136 + l]        = (_Float16)(mu + sq * e0);
        s_z2[(s0 + 4) * 136 + l]  = (_Float16)(mu + sq * e1);
        if (tid < 256) s_z2[(s0 + 8) * 136 + l] = (_Float16)(mu + sq * e2);
        if (tid < 128) gstore(&g_muq[pb * 128 + tid], mu);
      }
      __syncthreads();                       // B3 (pre-barrier vmcnt(0) drains all g_* stores)

      // publish progress: timestep t's five g_* arrays are device-visible now
      if (tid == 0)
        __hip_atomic_store(&prog[b], t + 1, __ATOMIC_RELAXED, __HIP_MEMORY_SCOPE_AGENT);

      // z_hat via MFMA: wave wv -> cols [16wv,16wv+16), rows = samples
      {
        uint4 a[4];
        #pragma unroll
        for (int ks = 0; ks < 4; ++ks)
          a[ks] = *(const uint4*)&s_z2[l15 * 136 + ks * 32 + quad * 8];
        f32x4 acc = {bz, bz, bz, bz};
        #pragma unroll
        for (int ks = 0; ks < 4; ++ks)
          acc = mfma16(a[ks], BFpz[(wv * 4 + ks) * 64 + lane], acc);
        #pragma unroll
        for (int r = 0; r < 4; ++r) {
          int s = quad * 4 + r;
          if (s < 10)
            s_zh2[s * 136 + 16 * wv + l15] = (_Float16)fmaxf(acc[r], 0.f);
        }
      }
      // gates-x: fdot2, row tid, result to s_gxh
      {
        float4 a4 = {blst, 0.f, 0.f, 0.f};
        #pragma unroll 4
        for (int k8 = 0; k8 < 16; ++k8) {
          uint4 w = Wihx4[k8 * 512 + tid];
          uint4 xv = *(const uint4*)&s_xh2[k8 * 4];
          dotacc4(w, xv, a4);
        }
        s_gxh[tid] = hsum4(a4);
      }
      __syncthreads();                       // B4

      // gates-z via MFMA: wave wv, nt=gate, cols 128*nt + 16*wv + l15
      {
        uint4 a[4];
        #pragma unroll
        for (int ks = 0; ks < 4; ++ks)
          a[ks] = *(const uint4*)&s_zh2[l15 * 136 + ks * 32 + quad * 8];
        #pragma unroll
        for (int nt = 0; nt < 4; ++nt) {
          float gx = s_gxh[128 * nt + 16 * wv + l15];
          f32x4 acc = {gx, gx, gx, gx};
          #pragma unroll
          for (int ks = 0; ks < 4; ++ks)
            acc = mfma16(a[ks], BFihz[((wv * 4 + nt) * 4 + ks) * 64 + lane], acc);
          #pragma unroll
          for (int r = 0; r < 4; ++r) {
            int s = quad * 4 + r;
            if (s < 10)
              s_gz[s * 512 + 128 * nt + 16 * wv + l15] = acc[r];
          }
        }
      }
      // whh B-frags rematerialized per timestep (64 VGPR, serial-section live range)
      uint4 whhf[16];
      #pragma unroll
      for (int i = 0; i < 16; ++i) whhf[i] = BFhh[(wv * 16 + i) * 64 + lane];
      __syncthreads();                       // B5

      // serial LSTM over 10 samples; M=1 broadcast-A MFMA (D rows identical)
      for (int s = 0; s < 10; ++s) {
        uint4 a[4];
        #pragma unroll
        for (int ks = 0; ks < 4; ++ks)
          a[ks] = *(const uint4*)&s_h2[ks * 32 + quad * 8];
        f32x4 acc[4];
        #pragma unroll
        for (int nt = 0; nt < 4; ++nt) {
          float cz = s_gz[s * 512 + 128 * nt + 16 * wv + l15];
          acc[nt] = f32x4{cz, cz, cz, cz};
        }
        __syncthreads();                     // all h reads done before h write
        #pragma unroll
        for (int nt = 0; nt < 4; ++nt)
          #pragma unroll
          for (int ks = 0; ks < 4; ++ks)
            acc[nt] = mfma16(a[ks], whhf[nt * 4 + ks], acc[nt]);
        if (lane < 16) {
          float gi = acc[0][0], gf = acc[1][0], gg = acc[2][0], go = acc[3][0];
          c_reg = sigm(gf) * c_reg + sigm(gi) * tanhf(gg);
          float h = sigm(go) * tanhf(c_reg);
          oacc += h;
          s_h2[16 * wv + lane] = (_Float16)h;
        }
        __syncthreads();
      }
      if (lane < 16) s_out[16 * wv + lane] = oacc * 0.1f;
    }
  } else {
    // ================= consumer: phase2, 512-thread chunks =================
    __shared__ __align__(16) _Float16 c_z2[5120];
    __shared__ __align__(16) _Float16 c_zh2[5120];
    __shared__ __align__(16) unsigned c_out2[256];
    __shared__ __align__(16) float c_muq[512], c_sgq[512], c_mup[512], c_sgp[512];
    __shared__ float c_wred[8];

    const int cid = blockIdx.x - 128;
    const float beta = beta_p[0];

    for (int c = cid; c < 3072; c += 128) {
      const int p0 = c * 4;            // 4 pairs, all same timestep
      const int t = p0 >> 7;
      const int b0 = p0 & 127;

      if (tid < 4) {
        while (__hip_atomic_load(&prog[b0 + tid], __ATOMIC_RELAXED,
                                 __HIP_MEMORY_SCOPE_AGENT) <= t)
          __builtin_amdgcn_s_sleep(8);
      }
      __syncthreads();                 // flags seen; also guards LDS reuse

      float acc_loc = 0.f;
      {
        size_t gi = (size_t)p0 * 128 + tid;
        c_muq[tid] = gload(g_muq + gi); c_sgq[tid] = gload(g_sgq + gi);
        c_mup[tid] = gload(g_mup + gi); c_sgp[tid] = gload(g_sgp + gi);
      }
      if (tid < 256) {
        int pair = tid >> 6, m = tid & 63;
        const float* o = g_out + (size_t)p0 * 128 + pair * 128;
        c_out2[tid] = packf16(gload(o + 2*m), gload(o + 2*m + 1));
      }
      __syncthreads();

      // z + KL: one (pp,l) per thread
      {
        int l = tid & 127, pp = tid >> 7;
        float mq = c_muq[pp*128 + l], sq = c_sgq[pp*128 + l];
        float mp = c_mup[pp*128 + l], spv = c_sgp[pp*128 + l];
        float inv_sp = 1.f / spv;
        float lsq = __logf(sq), lsp = __logf(spv);
        const float* ep = eps + (size_t)(p0 + pp) * 1280 + l;
        float kl = 0.f;
        #pragma unroll
        for (int s = 0; s < 10; ++s) {
          float e = ep[s * 128];
          float z = mq + sq * e;
          c_z2[(pp * 10 + s) * 128 + l] = (_Float16)z;
          float ap = (z - mp) * inv_sp;
          kl += (-0.5f * e * e - lsq) - (-0.5f * ap * ap - lsp);
        }
        acc_loc -= beta * kl;
      }
      __syncthreads();

      // z_hat: grp handles rows [grp*10, grp*10+10)
      {
        int j = tid & 127, grp = tid >> 7;
        float acc[10];
        float bj = b_pz[j];
        #pragma unroll
        for (int u = 0; u < 10; ++u) acc[u] = bj;
        for (int k8 = 0; k8 < 16; ++k8) {
          uint4 w = Wpz4[k8 * 128 + j];
          #pragma unroll
          for (int u = 0; u < 10; ++u) {
            uint4 zv = *(const uint4*)&c_z2[(grp * 10 + u) * 128 + k8 * 8];
            acc[u] = fdot2(w.x, zv.x, acc[u]); acc[u] = fdot2(w.y, zv.y, acc[u]);
            acc[u] = fdot2(w.z, zv.z, acc[u]); acc[u] = fdot2(w.w, zv.w, acc[u]);
          }
        }
        #pragma unroll
        for (int u = 0; u < 10; ++u)
          c_zh2[(grp * 10 + u) * 128 + j] = (_Float16)fmaxf(acc[u], 0.f);
      }
      __syncthreads();

      // decoder + Bernoulli log-prob
      for (int dc = 0; dc < 2; ++dc) {
        int d = tid + 512 * dc;
        if (d < 800) {
          float acco[4] = {0.f, 0.f, 0.f, 0.f};
          #pragma unroll 4
          for (int k8 = 0; k8 < 16; ++k8) {
            uint4 w = Wdeo4[k8 * 800 + d];
            #pragma unroll
            for (int pp = 0; pp < 4; ++pp) {
              uint4 ov = *(const uint4*)&c_out2[pp * 64 + k8 * 4];
              acco[pp] = fdot2(w.x, ov.x, acco[pp]); acco[pp] = fdot2(w.y, ov.y, acco[pp]);
              acco[pp] = fdot2(w.z, ov.z, acco[pp]); acco[pp] = fdot2(w.w, ov.w, acco[pp]);
            }
          }
          float bd = b_de[d];
          for (int pp = 0; pp < 4; ++pp) {
            float acc[10];
            #pragma unroll
            for (int s = 0; s < 10; ++s) acc[s] = 0.f;
            #pragma unroll 4
            for (int k8 = 0; k8 < 16; ++k8) {
              uint4 w = Wdez4[k8 * 800 + d];
              #pragma unroll
              for (int s = 0; s < 10; ++s) {
                uint4 zv = *(const uint4*)&c_zh2[(pp * 10 + s) * 128 + k8 * 8];
                acc[s] = fdot2(w.x, zv.x, acc[s]); acc[s] = fdot2(w.y, zv.y, acc[s]);
                acc[s] = fdot2(w.z, zv.z, acc[s]); acc[s] = fdot2(w.w, zv.w, acc[s]);
              }
            }
            int p = p0 + pp, tt2 = p >> 7, bb = p & 127;
            float xd = x[((size_t)bb * TT + tt2) * 800 + d];
            float base = acco[pp] + bd;
            #pragma unroll
            for (int s = 0; s < 10; ++s) {
              float lg = fmaxf(acc[s] + base, 0.f);
              acc_loc += xd * lg - lg - __logf(1.f + __expf(-lg));
            }
          }
        }
      }

      float v = acc_loc;
      #pragma unroll
      for (int off = 32; off > 0; off >>= 1) v += __shfl_down(v, off, 64);
      if ((tid & 63) == 0) c_wred[tid >> 6] = v;
      __syncthreads();
      if (tid == 0) {
        double tot = 0.0;
        #pragma unroll
        for (int w = 0; w < 8; ++w) tot += (double)c_wred[w];
        atomicAdd(accum, tot);
      }
      __syncthreads();                 // c_wred / LDS safe for next chunk
    }
  }
}

__global__ void finalize_kernel(const double* __restrict__ accum, float* __restrict__ out) {
  if (threadIdx.x == 0 && blockIdx.x == 0)
    out[0] = (float)(-accum[0] / 122880.0);   // B*T*S
}

// ---------------- host ----------------
extern "C" void kernel_launch(void* const* d_in, const int* in_sizes, int n_in,
                              void* d_out, int out_size, void* d_ws, size_t ws_size,
                              hipStream_t stream) {
  const float* x    = (const float*)d_in[0];
  const float* beta = (const float*)d_in[1];
  const float* eps  = (const float*)d_in[2];
  const float* W_px = (const float*)d_in[3];
  const float* b_px = (const float*)d_in[4];
  const float* W_pz = (const float*)d_in[5];
  const float* b_pz = (const float*)d_in[6];
  const float* W_pr = (const float*)d_in[7];
  const float* b_pr = (const float*)d_in[8];
  const float* W_en = (const float*)d_in[9];
  const float* b_en = (const float*)d_in[10];
  const float* W_de = (const float*)d_in[11];
  const float* b_de = (const float*)d_in[12];
  const float* W_ih = (const float*)d_in[13];
  const float* W_hh = (const float*)d_in[14];
  const float* b_ih = (const float*)d_in[15];
  const float* b_hh = (const float*)d_in[16];
  float* ws = (float*)d_ws;

  prep_misc<<<dim3(1), dim3(512), 0, stream>>>(b_ih, b_hh, ws + O_BL,
                                               (double*)(ws + O_ACC), (int*)(ws + O_PROG));

  auto pk = [&](const float* src, size_t off, int J, int rs, int k0, int K) {
    int total = J * (K / 2);
    prep_pack_f16<<<dim3((total + 255) / 256), dim3(256), 0, stream>>>(
        src, (unsigned*)(ws + off), J, rs, k0, total);
  };
  pk(W_pr, O_WPR, 256, 128, 0, 128);
  pk(W_en, O_WEN, 256, 256, 0, 256);
  pk(W_pz, O_WPZ, 128, 128, 0, 128);
  pk(W_ih, O_WIHX, 512, 256, 0, 128);
  pk(W_de, O_WDEZ, 800, 256, 0, 128);
  pk(W_de, O_WDEO, 800, 256, 128, 128);
  prep_bfrag<<<dim3(128), dim3(256), 0, stream>>>(W_ih, (unsigned*)(ws + O_BFIZ), 256, 128, 4, 0, 32768);
  prep_bfrag<<<dim3(128), dim3(256), 0, stream>>>(W_hh, (unsigned*)(ws + O_BFHH), 128, 0, 4, 0, 32768);
  prep_bfrag<<<dim3(32),  dim3(256), 0, stream>>>(W_pz, (unsigned*)(ws + O_BFPZ), 128, 0, 4, 1, 8192);
  prep_transpose<<<dim3((102400 + 255) / 256), dim3(256), 0, stream>>>(
      W_px, ws + O_WPX, 128, 800, 0, 102400);

  xhat_kernel<<<dim3(1536), dim3(256), 0, stream>>>(x, ws + O_WPX, b_px, (unsigned*)(ws + O_XHAT));

  // fused cooperative producer/consumer launch: 128 phase1 chains + 128 phase2 consumers
  {
    const unsigned* xhat2g = (const unsigned*)(ws + O_XHAT);
    const uint4* Wpr4  = (const uint4*)(ws + O_WPR);
    const uint4* Wen4  = (const uint4*)(ws + O_WEN);
    const uint4* BFpz  = (const uint4*)(ws + O_BFPZ);
    const uint4* Wihx4 = (const uint4*)(ws + O_WIHX);
    const uint4* BFihz = (const uint4*)(ws + O_BFIZ);
    const uint4* BFhh  = (const uint4*)(ws + O_BFHH);
    const float* b_lstm = ws + O_BL;
    float* g_out = ws + O_OUT;
    float* g_muq = ws + O_MUQ;
    float* g_sgq = ws + O_SGQ;
    float* g_mup = ws + O_MUP;
    float* g_sgp = ws + O_SGP;
    const uint4* Wpz4  = (const uint4*)(ws + O_WPZ);
    const uint4* Wdez4 = (const uint4*)(ws + O_WDEZ);
    const uint4* Wdeo4 = (const uint4*)(ws + O_WDEO);
    double* accum = (double*)(ws + O_ACC);
    int* prog = (int*)(ws + O_PROG);

    void* kargs[] = {
      (void*)&eps, (void*)&xhat2g,
      (void*)&Wpr4, (void*)&b_pr, (void*)&Wen4, (void*)&b_en,
      (void*)&BFpz, (void*)&b_pz, (void*)&Wihx4, (void*)&BFihz,
      (void*)&BFhh, (void*)&b_lstm,
      (void*)&g_out, (void*)&g_muq, (void*)&g_sgq, (void*)&g_mup, (void*)&g_sgp,
      (void*)&x, (void*)&beta,
      (void*)&Wpz4, (void*)&Wdez4, (void*)&Wdeo4, (void*)&b_de,
      (void*)&accum, (void*)&prog
    };
    hipLaunchCooperativeKernel((void*)fused_kernel, dim3(256), dim3(512),
                               kargs, 0, stream);
  }

  finalize_kernel<<<dim3(1), dim3(64), 0, stream>>>((const double*)(ws + O_ACC), (float*)d_out);
}

// Round 2
// 1374.351 us; speedup vs baseline: 1.2239x; 1.0479x over previous
//
#include <hip/hip_runtime.h>
#include <math.h>

#define TT 96
#define BB 128
#define DD 800
#define LL 128

typedef _Float16 h2v __attribute__((ext_vector_type(2)));
typedef _Float16 f16x8 __attribute__((ext_vector_type(8)));
typedef float f32x4 __attribute__((ext_vector_type(4)));

// ---- ws layout (4B units), shared host/device ----
constexpr size_t O_WPX  = 0;                      // 102400 fp32
constexpr size_t O_WPR  = O_WPX  + 102400;        // 16384 uints (fdot2 pack)
constexpr size_t O_WEN  = O_WPR  + 16384;         // 32768
constexpr size_t O_WPZ  = O_WEN  + 32768;         // 8192 (unused now, kept for layout)
constexpr size_t O_WIHX = O_WPZ  + 8192;          // 32768
constexpr size_t O_BFIZ = O_WIHX + 32768;         // 32768 (MFMA B-frags W_ihz^T)
constexpr size_t O_BFHH = O_BFIZ + 32768;         // 32768 (MFMA B-frags W_hh^T)
constexpr size_t O_BFDE = O_BFHH + 32768;         // 102400 (MFMA B-frags W_de^T, K=256)
constexpr size_t O_BL   = O_BFDE + 102400;        // 512
constexpr size_t O_ACC  = O_BL   + 512;           // 2 (double)
constexpr size_t O_XHAT = O_ACC  + 4;             // 786432 uints used
constexpr size_t O_BFPZ = O_XHAT + 786432;        // 8192 (MFMA B-frags W_pz^T)
constexpr size_t O_PROG = O_XHAT + 800000;        // 128 ints (progress flags, in XHAT gap)
constexpr size_t O_OUT  = O_XHAT + 1572864;
constexpr size_t O_MUQ  = O_OUT  + 1572864;
constexpr size_t O_SGQ  = O_MUQ  + 1572864;
constexpr size_t O_MUP  = O_SGQ  + 1572864;
constexpr size_t O_SGP  = O_MUP  + 1572864;

__device__ __forceinline__ h2v u2h(unsigned u) {
  union { unsigned u; h2v h; } x; x.u = u; return x.h;
}
__device__ __forceinline__ float fdot2(unsigned w, unsigned v, float acc) {
  return __builtin_amdgcn_fdot2(u2h(w), u2h(v), acc, false);
}
__device__ __forceinline__ unsigned packf16(float a, float b) {
  union { _Float16 h[2]; unsigned u; } x;
  x.h[0] = (_Float16)a; x.h[1] = (_Float16)b;
  return x.u;
}
__device__ __forceinline__ f16x8 u4h8(uint4 u) {
  union { uint4 u; f16x8 h; } x; x.u = u; return x.h;
}
__device__ __forceinline__ f32x4 mfma16(uint4 a, uint4 b, f32x4 c) {
  return __builtin_amdgcn_mfma_f32_16x16x32_f16(u4h8(a), u4h8(b), c, 0, 0, 0);
}
__device__ __forceinline__ float sigm(float x) { return 1.f/(1.f + __expf(-x)); }
__device__ __forceinline__ float hsum4(float4 a) { return (a.x + a.y) + (a.z + a.w); }

__device__ __forceinline__ void dotacc4(uint4 wv, uint4 vv, float4& av) {
  av.x = fdot2(wv.x, vv.x, av.x);
  av.y = fdot2(wv.y, vv.y, av.y);
  av.z = fdot2(wv.z, vv.z, av.z);
  av.w = fdot2(wv.w, vv.w, av.w);
}

// device-visible (agent-scope, sc1) stores/loads for cross-XCD producer->consumer handoff
__device__ __forceinline__ void gstore(float* p, float v) {
  __hip_atomic_store(p, v, __ATOMIC_RELAXED, __HIP_MEMORY_SCOPE_AGENT);
}
__device__ __forceinline__ float gload(const float* p) {
  return __hip_atomic_load(p, __ATOMIC_RELAXED, __HIP_MEMORY_SCOPE_AGENT);
}

// ---------------- prep ----------------
__global__ void prep_misc(const float* __restrict__ b_ih, const float* __restrict__ b_hh,
                          float* __restrict__ b_lstm, double* __restrict__ accum,
                          int* __restrict__ prog) {
  int t = threadIdx.x;
  if (t < 512) b_lstm[t] = b_ih[t] + b_hh[t];
  if (t == 0) accum[0] = 0.0;
  if (t < 128) __hip_atomic_store(&prog[t], 0, __ATOMIC_RELAXED, __HIP_MEMORY_SCOPE_AGENT);
}

// f16 interleaved pack (fdot2 layout)
__global__ void prep_pack_f16(const float* __restrict__ src, unsigned* __restrict__ dst,
                              int J, int rs, int k0, int total) {
  int idx = blockIdx.x * 256 + threadIdx.x;
  if (idx >= total) return;
  int u = idx & 3;
  int t2 = idx >> 2;
  int k8 = t2 / J;
  int j = t2 - k8 * J;
  int k = k8 * 8 + u * 2;
  const float* r = src + (size_t)j * rs + k0 + k;
  dst[idx] = packf16(r[0], r[1]);
}

// MFMA B-fragment layout pack: B = W^T; lane holds B[k][n] with n-part = lane&15,
// k = ks*32 + (lane>>4)*8 + j.
//  mode0 (N=512, gates): n = 128*(g&3) + 16*(g>>2) + (lane&15)
//  mode1:                n = 16*g + (lane&15)
__global__ void prep_bfrag(const float* __restrict__ src, unsigned* __restrict__ dst,
                           int rs, int k0, int KS, int mode, int total) {
  int idx = blockIdx.x * 256 + threadIdx.x;
  if (idx >= total) return;
  int jj = idx & 3;
  int lane = (idx >> 2) & 63;
  int t2 = idx >> 8;
  int ks = t2 % KS;
  int g = t2 / KS;
  int n = (mode == 0) ? (128 * (g & 3) + 16 * (g >> 2) + (lane & 15))
                      : (16 * g + (lane & 15));
  int k = ks * 32 + (lane >> 4) * 8 + jj * 2;
  const float* r = src + (size_t)n * rs + k0 + k;
  dst[idx] = packf16(r[0], r[1]);
}

// fp32 interleaved transpose (for W_px)
__global__ void prep_transpose(const float* __restrict__ src, float* __restrict__ dst,
                               int J, int rs, int k0, int total) {
  int idx = blockIdx.x * 256 + threadIdx.x;
  if (idx >= total) return;
  int J4 = J * 4;
  int k4 = idx / J4;
  int rem = idx - k4 * J4;
  int j = rem >> 2;
  int kk = rem & 3;
  dst[idx] = src[j * rs + k0 + k4 * 4 + kk];
}

// ---------------- phase 0: x_hat (emits f16-packed pairs) ----------------
__device__ __forceinline__ float dot4(float4 w, float4 v) {
  return w.x*v.x + w.y*v.y + w.z*v.z + w.w*v.w;
}
__global__ __launch_bounds__(256) void xhat_kernel(const float* __restrict__ x,
                                                   const float* __restrict__ Wpx4,
                                                   const float* __restrict__ b_px,
                                                   unsigned* __restrict__ xhat2) {
  __shared__ __align__(16) float sx[8][800];
  const int wg = blockIdx.x, tid = threadIdx.x;
  const int p0 = wg * 8;
  for (int r = 0; r < 8; ++r) {
    int p = p0 + r; int t = p >> 7; int b = p & 127;
    const float* row = x + ((size_t)b * TT + t) * 800;
    for (int col = tid; col < 800; col += 256) sx[r][col] = row[col];
  }
  __syncthreads();
  const int j = tid & 127, g = tid >> 7;
  float acc[4];
  const float bj = b_px[j];
  #pragma unroll
  for (int u = 0; u < 4; ++u) acc[u] = bj;
  const float4* W = (const float4*)Wpx4;
  #pragma unroll 2
  for (int k4 = 0; k4 < 200; ++k4) {
    float4 w = W[k4 * 128 + j];
    #pragma unroll
    for (int u = 0; u < 4; ++u) {
      float4 xv = *(const float4*)&sx[g + 2*u][k4 * 4];
      acc[u] += dot4(w, xv);
    }
  }
  #pragma unroll
  for (int u = 0; u < 4; ++u) {
    float v = fmaxf(acc[u], 0.f);
    float vp = __shfl_xor(v, 1, 64);
    if ((j & 1) == 0) {
      int p = p0 + g + 2*u;
      xhat2[(size_t)p * 64 + (j >> 1)] = packf16(v, vp);
    }
  }
}

// ---------------- fused producer/consumer kernel ----------------
// Blocks [0,128): phase1 producer, one batch chain each. R2 changes:
//   - B0/B1 merged (s_xh2 written pre-barrier; s_out2 packed by LSTM writer)
//   - all five g_* sc1 stores batched post-B3, drain hides under z_hat/gates-x,
//     flag published after B4 (whose pre-barrier vmcnt(0) drains the stores)
//   - serial LSTM double-buffers h: one barrier per sample (10 vs 20)
//   => 15 barriers/timestep vs 26.
// Blocks [128,256): phase2 consumers, MFMA-ized:
//   z_hat = MFMA M=40(+8 pad) N=128 K=128 reusing BFpz; decoder = single GEMM
//   M=40 N=800 K=256 over A=[z_hat|out] with BFde frags. Pad rows 40-47 carry
//   garbage that only ever lands in discarded output rows (MFMA row m reads
//   A row m only).
__global__ __launch_bounds__(512) void fused_kernel(
    const float* __restrict__ eps, const unsigned* __restrict__ xhat2g,
    const uint4* __restrict__ Wpr4, const float* __restrict__ b_pr,
    const uint4* __restrict__ Wen4, const float* __restrict__ b_en,
    const uint4* __restrict__ BFpz, const float* __restrict__ b_pz,
    const uint4* __restrict__ Wihx4, const uint4* __restrict__ BFihz,
    const uint4* __restrict__ BFhh, const float* __restrict__ b_lstm,
    float* __restrict__ g_out, float* __restrict__ g_muq, float* __restrict__ g_sgq,
    float* __restrict__ g_mup, float* __restrict__ g_sgp,
    const float* __restrict__ x, const float* __restrict__ beta_p,
    const uint4* __restrict__ BFde, const float* __restrict__ b_de,
    double* __restrict__ accum, int* __restrict__ prog)
{
  const int tid = threadIdx.x;

  if (blockIdx.x < 128) {
    // ================= producer: phase1 =================
    __shared__ __align__(16) float s_gz[5120];        // [10][512] gate pre-acts
    __shared__ __align__(16) _Float16 s_z2[16*136];   // padded rows (stride 136)
    __shared__ __align__(16) _Float16 s_zh2[16*136];
    __shared__ __align__(16) float s_gxh[512];
    __shared__ __align__(16) float s_out[128];
    __shared__ __align__(16) float s_ehmu[128];
    __shared__ __align__(16) float s_mup[128];
    __shared__ __align__(16) float s_sgp[128];
    __shared__ __align__(16) float s_sgq[128];
    __shared__ __align__(16) unsigned s_out2[64];
    __shared__ __align__(16) unsigned s_xh2[64];
    __shared__ __align__(16) _Float16 s_h2[2][128];   // double-buffered h

    const int b = blockIdx.x;
    const int wv = tid >> 6;
    const int lane = tid & 63;
    const int l15 = lane & 15;
    const int quad = lane >> 4;

    if (tid < 128) { s_out[tid] = 0.f; s_h2[0][tid] = (_Float16)0.f; }
    if (tid < 64) s_out2[tid] = 0u;
    float c_reg = 0.f;                       // lanes<16: cell state for h-idx 16*wv+lane
    const float blst = b_lstm[tid];
    const float bias_pe = (tid < 256) ? b_pr[tid] : b_en[tid - 256];
    const float bz = b_pz[16 * wv + l15];

    for (int t = 0; t < TT; ++t) {
      const size_t pb = (size_t)t * BB + b;
      const float* epsb = eps + pb * 1280;
      float e0 = epsb[tid];
      float e1 = epsb[tid + 512];
      float e2 = (tid < 256) ? epsb[tid + 1024] : 0.f;
      // s_xh2 safe to write pre-barrier: its last reader (gates-x) was before
      // B4 of timestep t-1.
      if (tid >= 192 && tid < 256) s_xh2[tid - 192] = xhat2g[pb * 64 + (tid - 192)];

      __syncthreads();                       // B0: prev s_out/s_out2/s_h2 + s_xh2 visible

      // prior (tid<256) / encoder (tid>=256): fdot2, weights streamed from L2
      {
        float4 a4 = {bias_pe, 0.f, 0.f, 0.f};
        if (tid < 256) {
          #pragma unroll 4
          for (int k8 = 0; k8 < 16; ++k8) {
            uint4 w = Wpr4[k8 * 256 + tid];
            uint4 o = *(const uint4*)&s_out2[k8 * 4];
            dotacc4(w, o, a4);
          }
          float ph = fmaxf(hsum4(a4), 0.f);
          if (tid < 128) s_mup[tid] = ph;
          else {
            float y = expf(ph) + 0.5f;
            float sp = (y > 20.f) ? y : log1pf(expf(y));
            s_sgp[tid - 128] = sp;
          }
        } else {
          int j2 = tid - 256;
          #pragma unroll 4
          for (int k8 = 0; k8 < 16; ++k8) {
            uint4 w = Wen4[k8 * 256 + j2];
            uint4 o = *(const uint4*)&s_out2[k8 * 4];
            dotacc4(w, o, a4);
          }
          #pragma unroll 4
          for (int k8 = 16; k8 < 32; ++k8) {
            uint4 w = Wen4[k8 * 256 + j2];
            uint4 o = *(const uint4*)&s_xh2[(k8 - 16) * 4];
            dotacc4(w, o, a4);
          }
          float eh = fmaxf(hsum4(a4), 0.f);
          if (j2 < 128) s_ehmu[j2] = eh;
          else { float sq = expf(eh); s_sgq[j2 - 128] = sq; }
        }
      }
      __syncthreads();                       // B2

      // z into padded s_z2 rows (sample = row)
      {
        int l = tid & 127, s0 = tid >> 7;
        float mu = s_ehmu[l] + s_mup[l];
        float sq = s_sgq[l];
        s_z2[s0 * 136 + l]        = (_Float16)(mu + sq * e0);
        s_z2[(s0 + 4) * 136 + l]  = (_Float16)(mu + sq * e1);
        if (tid < 256) s_z2[(s0 + 8) * 136 + l] = (_Float16)(mu + sq * e2);
      }
      __syncthreads();                       // B3

      // batched sc1 publication of timestep t; latency hides under z_hat/gates-x,
      // drained by B4's pre-barrier vmcnt(0).
      if (tid < 128) {
        gstore(&g_muq[pb * 128 + tid], s_ehmu[tid] + s_mup[tid]);
        gstore(&g_sgq[pb * 128 + tid], s_sgq[tid]);
      } else if (tid < 256) {
        gstore(&g_out[pb * 128 + tid - 128], s_out[tid - 128]);
      } else if (tid < 384) {
        gstore(&g_mup[pb * 128 + tid - 256], s_mup[tid - 256]);
      } else {
        gstore(&g_sgp[pb * 128 + tid - 384], s_sgp[tid - 384]);
      }

      // z_hat via MFMA: wave wv -> cols [16wv,16wv+16), rows = samples
      {
        uint4 a[4];
        #pragma unroll
        for (int ks = 0; ks < 4; ++ks)
          a[ks] = *(const uint4*)&s_z2[l15 * 136 + ks * 32 + quad * 8];
        f32x4 acc = {bz, bz, bz, bz};
        #pragma unroll
        for (int ks = 0; ks < 4; ++ks)
          acc = mfma16(a[ks], BFpz[(wv * 4 + ks) * 64 + lane], acc);
        #pragma unroll
        for (int r = 0; r < 4; ++r) {
          int s = quad * 4 + r;
          if (s < 10)
            s_zh2[s * 136 + 16 * wv + l15] = (_Float16)fmaxf(acc[r], 0.f);
        }
      }
      // gates-x: fdot2, row tid, result to s_gxh
      {
        float4 a4 = {blst, 0.f, 0.f, 0.f};
        #pragma unroll 4
        for (int k8 = 0; k8 < 16; ++k8) {
          uint4 w = Wihx4[k8 * 512 + tid];
          uint4 xv = *(const uint4*)&s_xh2[k8 * 4];
          dotacc4(w, xv, a4);
        }
        s_gxh[tid] = hsum4(a4);
      }
      __syncthreads();                       // B4 (drains the g_* stores)

      // publish progress: timestep t's five g_* arrays are device-visible now
      if (tid == 0)
        __hip_atomic_store(&prog[b], t + 1, __ATOMIC_RELAXED, __HIP_MEMORY_SCOPE_AGENT);

      // gates-z via MFMA: wave wv, nt=gate, cols 128*nt + 16*wv + l15
      {
        uint4 a[4];
        #pragma unroll
        for (int ks = 0; ks < 4; ++ks)
          a[ks] = *(const uint4*)&s_zh2[l15 * 136 + ks * 32 + quad * 8];
        #pragma unroll
        for (int nt = 0; nt < 4; ++nt) {
          float gx = s_gxh[128 * nt + 16 * wv + l15];
          f32x4 acc = {gx, gx, gx, gx};
          #pragma unroll
          for (int ks = 0; ks < 4; ++ks)
            acc = mfma16(a[ks], BFihz[((wv * 4 + nt) * 4 + ks) * 64 + lane], acc);
          #pragma unroll
          for (int r = 0; r < 4; ++r) {
            int s = quad * 4 + r;
            if (s < 10)
              s_gz[s * 512 + 128 * nt + 16 * wv + l15] = acc[r];
          }
        }
      }
      // whh B-frags rematerialized per timestep (64 VGPR, serial-section live range)
      uint4 whhf[16];
      #pragma unroll
      for (int i = 0; i < 16; ++i) whhf[i] = BFhh[(wv * 16 + i) * 64 + lane];
      __syncthreads();                       // B5

      // serial LSTM over 10 samples, double-buffered h: ONE barrier per sample.
      // s reads buf[s&1], writes buf[(s+1)&1]; the end-of-sample barrier orders
      // this write against both the next read of that buffer (s+1) and the
      // next write of the read buffer (s+1 writes buf[s&1]).
      float oacc = 0.f;
      for (int s = 0; s < 10; ++s) {
        const _Float16* hb = s_h2[s & 1];
        uint4 a[4];
        #pragma unroll
        for (int ks = 0; ks < 4; ++ks)
          a[ks] = *(const uint4*)&hb[ks * 32 + quad * 8];
        f32x4 acc[4];
        #pragma unroll
        for (int nt = 0; nt < 4; ++nt) {
          float cz = s_gz[s * 512 + 128 * nt + 16 * wv + l15];
          acc[nt] = f32x4{cz, cz, cz, cz};
        }
        #pragma unroll
        for (int nt = 0; nt < 4; ++nt)
          #pragma unroll
          for (int ks = 0; ks < 4; ++ks)
            acc[nt] = mfma16(a[ks], whhf[nt * 4 + ks], acc[nt]);
        if (lane < 16) {
          float gi = acc[0][0], gf = acc[1][0], gg = acc[2][0], go = acc[3][0];
          c_reg = sigm(gf) * c_reg + sigm(gi) * tanhf(gg);
          float h = sigm(go) * tanhf(c_reg);
          oacc += h;
          s_h2[(s + 1) & 1][16 * wv + lane] = (_Float16)h;
        }
        __syncthreads();
      }
      // 10 samples (even) -> final h sits in buf[0]; next timestep reads buf[0].
      if (lane < 16) {
        float v = oacc * 0.1f;
        s_out[16 * wv + lane] = v;
        float vn = __shfl_xor(v, 1, 64);
        if (!(lane & 1)) s_out2[8 * wv + (lane >> 1)] = packf16(v, vn);
      }
    }
  } else {
    // ================= consumer: phase2, MFMA-ized =================
    __shared__ __align__(16) _Float16 c_z2[48 * 128];   // z rows (40 + 8 pad)
    __shared__ __align__(16) _Float16 c_a2[48 * 256];   // [z_hat | out] GEMM A
    __shared__ __align__(16) float c_x[4 * 800];
    __shared__ __align__(16) unsigned c_out2[256];
    __shared__ __align__(16) float c_muq[512], c_sgq[512], c_mup[512], c_sgp[512];
    __shared__ float c_wred[8];

    const int cid = blockIdx.x - 128;
    const int wv = tid >> 6;
    const int lane = tid & 63;
    const int l15 = lane & 15;
    const int quad = lane >> 4;
    const float beta = beta_p[0];

    for (int c = cid; c < 3072; c += 128) {
      const int p0 = c * 4;            // 4 pairs, all same timestep
      const int t = p0 >> 7;
      const int b0 = p0 & 127;

      if (tid < 4) {
        while (__hip_atomic_load(&prog[b0 + tid], __ATOMIC_RELAXED,
                                 __HIP_MEMORY_SCOPE_AGENT) <= t)
          __builtin_amdgcn_s_sleep(8);
      }
      __syncthreads();                 // flags seen; also guards LDS reuse

      float acc_loc = 0.f;
      {
        size_t gi = (size_t)p0 * 128 + tid;
        c_muq[tid] = gload(g_muq + gi); c_sgq[tid] = gload(g_sgq + gi);
        c_mup[tid] = gload(g_mup + gi); c_sgp[tid] = gload(g_sgp + gi);
      }
      if (tid < 256) {
        int pair = tid >> 6, m = tid & 63;
        const float* o = g_out + (size_t)p0 * 128 + pair * 128;
        c_out2[tid] = packf16(gload(o + 2*m), gload(o + 2*m + 1));
      }
      // stage x rows for the 4 pairs
      for (int i = tid; i < 3200; i += 512) {
        int pp = i / 800;
        int d = i - pp * 800;
        int p = p0 + pp, bb = p & 127, tt2 = p >> 7;
        c_x[i] = x[((size_t)bb * TT + tt2) * 800 + d];
      }
      __syncthreads();

      // z + KL: one (pp,l) per thread
      {
        int l = tid & 127, pp = tid >> 7;
        float mq = c_muq[pp*128 + l], sq = c_sgq[pp*128 + l];
        float mp = c_mup[pp*128 + l], spv = c_sgp[pp*128 + l];
        float inv_sp = 1.f / spv;
        float lsq = __logf(sq), lsp = __logf(spv);
        const float* ep = eps + (size_t)(p0 + pp) * 1280 + l;
        float kl = 0.f;
        #pragma unroll
        for (int s = 0; s < 10; ++s) {
          float e = ep[s * 128];
          float z = mq + sq * e;
          c_z2[(pp * 10 + s) * 128 + l] = (_Float16)z;
          float ap = (z - mp) * inv_sp;
          kl += (-0.5f * e * e - lsq) - (-0.5f * ap * ap - lsp);
        }
        acc_loc -= beta * kl;
      }
      // out half of A: rows 0..39 get out[pp] in cols 128..255 (as u32 pairs)
      for (int i = tid; i < 2560; i += 512) {
        int r = i >> 6, m = i & 63;
        int pp = (r * 205) >> 11;      // r/10 for r<48
        ((unsigned*)c_a2)[r * 128 + 64 + m] = c_out2[pp * 64 + m];
      }
      __syncthreads();

      // z_hat via MFMA: M=48(40 used) N=128 K=128, reusing BFpz frags.
      // 24 (mt,nt) tiles over 8 waves.
      for (int tile = wv; tile < 24; tile += 8) {
        int mt = tile >> 3, nt = tile & 7;
        uint4 a[4];
        #pragma unroll
        for (int ks = 0; ks < 4; ++ks)
          a[ks] = *(const uint4*)&c_z2[(mt * 16 + l15) * 128 + ks * 32 + quad * 8];
        float bzt = b_pz[16 * nt + l15];
        f32x4 acc = {bzt, bzt, bzt, bzt};
        #pragma unroll
        for (int ks = 0; ks < 4; ++ks)
          acc = mfma16(a[ks], BFpz[(nt * 4 + ks) * 64 + lane], acc);
        #pragma unroll
        for (int r = 0; r < 4; ++r) {
          int row = mt * 16 + quad * 4 + r;
          c_a2[row * 256 + 16 * nt + l15] = (_Float16)fmaxf(acc[r], 0.f);
        }
      }
      __syncthreads();

      // decoder GEMM: M=48(40 used) N=800 K=256 + Bernoulli epilogue
      #pragma unroll
      for (int mt = 0; mt < 3; ++mt) {
        uint4 a[8];
        #pragma unroll
        for (int ks = 0; ks < 8; ++ks)
          a[ks] = *(const uint4*)&c_a2[(mt * 16 + l15) * 256 + ks * 32 + quad * 8];
        for (int nt = wv; nt < 50; nt += 8) {
          f32x4 acc = {0.f, 0.f, 0.f, 0.f};
          #pragma unroll
          for (int ks = 0; ks < 8; ++ks)
            acc = mfma16(a[ks], BFde[(nt * 8 + ks) * 64 + lane], acc);
          int d = 16 * nt + l15;
          float bd = b_de[d];
          #pragma unroll
          for (int r = 0; r < 4; ++r) {
            int row = mt * 16 + quad * 4 + r;
            if (row < 40) {
              int pp = (row * 205) >> 11;
              float lg = fmaxf(acc[r] + bd, 0.f);
              float xd = c_x[pp * 800 + d];
              acc_loc += xd * lg - lg - __logf(1.f + __expf(-lg));
            }
          }
        }
      }

      float v = acc_loc;
      #pragma unroll
      for (int off = 32; off > 0; off >>= 1) v += __shfl_down(v, off, 64);
      if ((tid & 63) == 0) c_wred[tid >> 6] = v;
      __syncthreads();
      if (tid == 0) {
        double tot = 0.0;
        #pragma unroll
        for (int w = 0; w < 8; ++w) tot += (double)c_wred[w];
        atomicAdd(accum, tot);
      }
      __syncthreads();                 // c_wred / LDS safe for next chunk
    }
  }
}

__global__ void finalize_kernel(const double* __restrict__ accum, float* __restrict__ out) {
  if (threadIdx.x == 0 && blockIdx.x == 0)
    out[0] = (float)(-accum[0] / 122880.0);   // B*T*S
}

// ---------------- host ----------------
extern "C" void kernel_launch(void* const* d_in, const int* in_sizes, int n_in,
                              void* d_out, int out_size, void* d_ws, size_t ws_size,
                              hipStream_t stream) {
  const float* x    = (const float*)d_in[0];
  const float* beta = (const float*)d_in[1];
  const float* eps  = (const float*)d_in[2];
  const float* W_px = (const float*)d_in[3];
  const float* b_px = (const float*)d_in[4];
  const float* W_pz = (const float*)d_in[5];
  const float* b_pz = (const float*)d_in[6];
  const float* W_pr = (const float*)d_in[7];
  const float* b_pr = (const float*)d_in[8];
  const float* W_en = (const float*)d_in[9];
  const float* b_en = (const float*)d_in[10];
  const float* W_de = (const float*)d_in[11];
  const float* b_de = (const float*)d_in[12];
  const float* W_ih = (const float*)d_in[13];
  const float* W_hh = (const float*)d_in[14];
  const float* b_ih = (const float*)d_in[15];
  const float* b_hh = (const float*)d_in[16];
  float* ws = (float*)d_ws;

  prep_misc<<<dim3(1), dim3(512), 0, stream>>>(b_ih, b_hh, ws + O_BL,
                                               (double*)(ws + O_ACC), (int*)(ws + O_PROG));

  auto pk = [&](const float* src, size_t off, int J, int rs, int k0, int K) {
    int total = J * (K / 2);
    prep_pack_f16<<<dim3((total + 255) / 256), dim3(256), 0, stream>>>(
        src, (unsigned*)(ws + off), J, rs, k0, total);
  };
  pk(W_pr, O_WPR, 256, 128, 0, 128);
  pk(W_en, O_WEN, 256, 256, 0, 256);
  pk(W_ih, O_WIHX, 512, 256, 0, 128);
  // MFMA B-frag packs
  prep_bfrag<<<dim3(128), dim3(256), 0, stream>>>(W_ih, (unsigned*)(ws + O_BFIZ), 256, 128, 4, 0, 32768);
  prep_bfrag<<<dim3(128), dim3(256), 0, stream>>>(W_hh, (unsigned*)(ws + O_BFHH), 128, 0, 4, 0, 32768);
  prep_bfrag<<<dim3(32),  dim3(256), 0, stream>>>(W_pz, (unsigned*)(ws + O_BFPZ), 128, 0, 4, 1, 8192);
  prep_bfrag<<<dim3(400), dim3(256), 0, stream>>>(W_de, (unsigned*)(ws + O_BFDE), 256, 0, 8, 1, 102400);
  prep_transpose<<<dim3((102400 + 255) / 256), dim3(256), 0, stream>>>(
      W_px, ws + O_WPX, 128, 800, 0, 102400);

  xhat_kernel<<<dim3(1536), dim3(256), 0, stream>>>(x, ws + O_WPX, b_px, (unsigned*)(ws + O_XHAT));

  // fused cooperative producer/consumer launch
  {
    const unsigned* xhat2g = (const unsigned*)(ws + O_XHAT);
    const uint4* Wpr4  = (const uint4*)(ws + O_WPR);
    const uint4* Wen4  = (const uint4*)(ws + O_WEN);
    const uint4* BFpz  = (const uint4*)(ws + O_BFPZ);
    const uint4* Wihx4 = (const uint4*)(ws + O_WIHX);
    const uint4* BFihz = (const uint4*)(ws + O_BFIZ);
    const uint4* BFhh  = (const uint4*)(ws + O_BFHH);
    const uint4* BFde  = (const uint4*)(ws + O_BFDE);
    const float* b_lstm = ws + O_BL;
    float* g_out = ws + O_OUT;
    float* g_muq = ws + O_MUQ;
    float* g_sgq = ws + O_SGQ;
    float* g_mup = ws + O_MUP;
    float* g_sgp = ws + O_SGP;
    double* accum = (double*)(ws + O_ACC);
    int* prog = (int*)(ws + O_PROG);

    void* kargs[] = {
      (void*)&eps, (void*)&xhat2g,
      (void*)&Wpr4, (void*)&b_pr, (void*)&Wen4, (void*)&b_en,
      (void*)&BFpz, (void*)&b_pz, (void*)&Wihx4, (void*)&BFihz,
      (void*)&BFhh, (void*)&b_lstm,
      (void*)&g_out, (void*)&g_muq, (void*)&g_sgq, (void*)&g_mup, (void*)&g_sgp,
      (void*)&x, (void*)&beta,
      (void*)&BFde, (void*)&b_de,
      (void*)&accum, (void*)&prog
    };
    hipLaunchCooperativeKernel((void*)fused_kernel, dim3(256), dim3(512),
                               kargs, 0, stream);
  }

  finalize_kernel<<<dim3(1), dim3(64), 0, stream>>>((const double*)(ws + O_ACC), (float*)d_out);
}

// Round 3
// 1260.328 us; speedup vs baseline: 1.3346x; 1.0905x over previous
//
#include <hip/hip_runtime.h>
#include <math.h>

#define TT 96
#define BB 128
#define DD 800
#define LL 128

typedef _Float16 h2v __attribute__((ext_vector_type(2)));
typedef _Float16 f16x8 __attribute__((ext_vector_type(8)));
typedef float f32x4 __attribute__((ext_vector_type(4)));

// ---- ws layout (4B units), shared host/device ----
constexpr size_t O_WPX  = 0;                      // 102400 fp32
constexpr size_t O_WPR  = O_WPX  + 102400;        // 16384 uints (fdot2 pack)
constexpr size_t O_WEN  = O_WPR  + 16384;         // 32768
constexpr size_t O_WPZ  = O_WEN  + 32768;         // 8192 (unused, layout keep)
constexpr size_t O_WIHX = O_WPZ  + 8192;          // 32768
constexpr size_t O_BFIZ = O_WIHX + 32768;         // 32768 (MFMA B-frags W_ihz^T)
constexpr size_t O_BFHH = O_BFIZ + 32768;         // 32768 (MFMA B-frags W_hh^T)
constexpr size_t O_BFDE = O_BFHH + 32768;         // 102400 (MFMA B-frags W_de^T, K=256)
constexpr size_t O_BL   = O_BFDE + 102400;        // 512
constexpr size_t O_ACC  = O_BL   + 512;           // 2 (double)
constexpr size_t O_XHAT = O_ACC  + 4;             // 786432 uints used
constexpr size_t O_BFPZ = O_XHAT + 786432;        // 8192 (MFMA B-frags W_pz^T)
constexpr size_t O_PROG = O_XHAT + 800000;        // 128 ints (progress flags)
constexpr size_t O_OUT  = O_XHAT + 1572864;       // 1572864 fp32
constexpr size_t O_Q2   = O_OUT  + 1572864;       // float2[12288*128] (muq,sgq)
constexpr size_t O_P2   = O_Q2   + 3145728;       // float2[12288*128] (mup,sgp)

__device__ __forceinline__ h2v u2h(unsigned u) {
  union { unsigned u; h2v h; } x; x.u = u; return x.h;
}
__device__ __forceinline__ float fdot2(unsigned w, unsigned v, float acc) {
  return __builtin_amdgcn_fdot2(u2h(w), u2h(v), acc, false);
}
__device__ __forceinline__ unsigned packf16(float a, float b) {
  union { _Float16 h[2]; unsigned u; } x;
  x.h[0] = (_Float16)a; x.h[1] = (_Float16)b;
  return x.u;
}
__device__ __forceinline__ f16x8 u4h8(uint4 u) {
  union { uint4 u; f16x8 h; } x; x.u = u; return x.h;
}
__device__ __forceinline__ f32x4 mfma16(uint4 a, uint4 b, f32x4 c) {
  return __builtin_amdgcn_mfma_f32_16x16x32_f16(u4h8(a), u4h8(b), c, 0, 0, 0);
}
__device__ __forceinline__ float frcp(float x) { return __builtin_amdgcn_rcpf(x); }
__device__ __forceinline__ float fsigm(float x) { return frcp(1.f + __expf(-x)); }
// tanh via exp2-based __expf; saturates correctly for large |x| (e=inf -> t=1)
__device__ __forceinline__ float ftanh(float x) {
  float e = __expf(2.f * fabsf(x));
  float t = 1.f - 2.f * frcp(e + 1.f);
  return copysignf(t, x);
}
__device__ __forceinline__ float hsum4(float4 a) { return (a.x + a.y) + (a.z + a.w); }

__device__ __forceinline__ void dotacc4(uint4 wv, uint4 vv, float4& av) {
  av.x = fdot2(wv.x, vv.x, av.x);
  av.y = fdot2(wv.y, vv.y, av.y);
  av.z = fdot2(wv.z, vv.z, av.z);
  av.w = fdot2(wv.w, vv.w, av.w);
}

// raw LDS-only barrier: orders LDS ops without draining vmcnt (the compiler's
// __syncthreads always drains vmcnt(0), exposing sc1-store latency).
// sched_barrier(0) fences per cdna guide rule #18.
__device__ __forceinline__ void bar_lds() {
  asm volatile("s_waitcnt lgkmcnt(0)" ::: "memory");
  __builtin_amdgcn_sched_barrier(0);
  __builtin_amdgcn_s_barrier();
  __builtin_amdgcn_sched_barrier(0);
}

// device-visible (agent-scope) stores/loads for cross-XCD producer->consumer handoff
__device__ __forceinline__ void gstore(float* p, float v) {
  __hip_atomic_store(p, v, __ATOMIC_RELAXED, __HIP_MEMORY_SCOPE_AGENT);
}
__device__ __forceinline__ float gload(const float* p) {
  return __hip_atomic_load(p, __ATOMIC_RELAXED, __HIP_MEMORY_SCOPE_AGENT);
}
__device__ __forceinline__ void gstore2(float2* p, float a, float b) {
  union { float f[2]; unsigned long long u; } x; x.f[0] = a; x.f[1] = b;
  __hip_atomic_store((unsigned long long*)p, x.u, __ATOMIC_RELAXED, __HIP_MEMORY_SCOPE_AGENT);
}
__device__ __forceinline__ float2 gload2(const float2* p) {
  unsigned long long u = __hip_atomic_load((const unsigned long long*)p,
                                           __ATOMIC_RELAXED, __HIP_MEMORY_SCOPE_AGENT);
  union { unsigned long long u; float2 f; } x; x.u = u; return x.f;
}

// consumer LDS XOR swizzle (T2): spreads same-column rows across banks.
// element-index form for f16 arrays; XOR touches bits 3-5 so 16B alignment holds.
__device__ __forceinline__ int swz128(int row, int col) {
  return row * 128 + (col ^ ((row & 7) << 3));
}
__device__ __forceinline__ int swz256(int row, int col) {
  return row * 256 + (col ^ ((row & 7) << 3));
}

// ---------------- prep ----------------
__global__ void prep_misc(const float* __restrict__ b_ih, const float* __restrict__ b_hh,
                          float* __restrict__ b_lstm, double* __restrict__ accum,
                          int* __restrict__ prog) {
  int t = threadIdx.x;
  if (t < 512) b_lstm[t] = b_ih[t] + b_hh[t];
  if (t == 0) accum[0] = 0.0;
  if (t < 128) __hip_atomic_store(&prog[t], 0, __ATOMIC_RELAXED, __HIP_MEMORY_SCOPE_AGENT);
}

// f16 interleaved pack (fdot2 layout)
__global__ void prep_pack_f16(const float* __restrict__ src, unsigned* __restrict__ dst,
                              int J, int rs, int k0, int total) {
  int idx = blockIdx.x * 256 + threadIdx.x;
  if (idx >= total) return;
  int u = idx & 3;
  int t2 = idx >> 2;
  int k8 = t2 / J;
  int j = t2 - k8 * J;
  int k = k8 * 8 + u * 2;
  const float* r = src + (size_t)j * rs + k0 + k;
  dst[idx] = packf16(r[0], r[1]);
}

// MFMA B-fragment layout pack: B = W^T; lane holds B[k][n] with n-part = lane&15,
// k = ks*32 + (lane>>4)*8 + j.
//  mode0 (N=512, gates): n = 128*(g&3) + 16*(g>>2) + (lane&15)
//  mode1:                n = 16*g + (lane&15)
__global__ void prep_bfrag(const float* __restrict__ src, unsigned* __restrict__ dst,
                           int rs, int k0, int KS, int mode, int total) {
  int idx = blockIdx.x * 256 + threadIdx.x;
  if (idx >= total) return;
  int jj = idx & 3;
  int lane = (idx >> 2) & 63;
  int t2 = idx >> 8;
  int ks = t2 % KS;
  int g = t2 / KS;
  int n = (mode == 0) ? (128 * (g & 3) + 16 * (g >> 2) + (lane & 15))
                      : (16 * g + (lane & 15));
  int k = ks * 32 + (lane >> 4) * 8 + jj * 2;
  const float* r = src + (size_t)n * rs + k0 + k;
  dst[idx] = packf16(r[0], r[1]);
}

// fp32 interleaved transpose (for W_px)
__global__ void prep_transpose(const float* __restrict__ src, float* __restrict__ dst,
                               int J, int rs, int k0, int total) {
  int idx = blockIdx.x * 256 + threadIdx.x;
  if (idx >= total) return;
  int J4 = J * 4;
  int k4 = idx / J4;
  int rem = idx - k4 * J4;
  int j = rem >> 2;
  int kk = rem & 3;
  dst[idx] = src[j * rs + k0 + k4 * 4 + kk];
}

// ---------------- phase 0: x_hat (emits f16-packed pairs) ----------------
__device__ __forceinline__ float dot4(float4 w, float4 v) {
  return w.x*v.x + w.y*v.y + w.z*v.z + w.w*v.w;
}
__global__ __launch_bounds__(256) void xhat_kernel(const float* __restrict__ x,
                                                   const float* __restrict__ Wpx4,
                                                   const float* __restrict__ b_px,
                                                   unsigned* __restrict__ xhat2) {
  __shared__ __align__(16) float sx[8][800];
  const int wg = blockIdx.x, tid = threadIdx.x;
  const int p0 = wg * 8;
  for (int r = 0; r < 8; ++r) {
    int p = p0 + r; int t = p >> 7; int b = p & 127;
    const float* row = x + ((size_t)b * TT + t) * 800;
    for (int col = tid; col < 800; col += 256) sx[r][col] = row[col];
  }
  __syncthreads();
  const int j = tid & 127, g = tid >> 7;
  float acc[4];
  const float bj = b_px[j];
  #pragma unroll
  for (int u = 0; u < 4; ++u) acc[u] = bj;
  const float4* W = (const float4*)Wpx4;
  #pragma unroll 2
  for (int k4 = 0; k4 < 200; ++k4) {
    float4 w = W[k4 * 128 + j];
    #pragma unroll
    for (int u = 0; u < 4; ++u) {
      float4 xv = *(const float4*)&sx[g + 2*u][k4 * 4];
      acc[u] += dot4(w, xv);
    }
  }
  #pragma unroll
  for (int u = 0; u < 4; ++u) {
    float v = fmaxf(acc[u], 0.f);
    float vp = __shfl_xor(v, 1, 64);
    if ((j & 1) == 0) {
      int p = p0 + g + 2*u;
      xhat2[(size_t)p * 64 + (j >> 1)] = packf16(v, vp);
    }
  }
}

// ---------------- fused producer/consumer kernel ----------------
// Producer (blocks 0-127): one batch chain each. R3: raw lgkm-only barriers
// everywhere except ONE full __syncthreads per timestep (B5, drains the sc1
// g_* stores; flag published after it). B0 eliminated via xhat register
// prefetch + epilogue s_xh2 write. whhf/bfpz frags VGPR-resident across the
// whole t-loop (1 block/CU by LDS, so ~205 VGPR is free at 2 waves/SIMD).
// Fast tanh/exp on the serial LSTM nonlinearity chain.
// Consumer (blocks 128-255): MFMA phase2 with XOR-swizzled c_z2/c_a2.
__global__ __launch_bounds__(512) void fused_kernel(
    const float* __restrict__ eps, const unsigned* __restrict__ xhat2g,
    const uint4* __restrict__ Wpr4, const float* __restrict__ b_pr,
    const uint4* __restrict__ Wen4, const float* __restrict__ b_en,
    const uint4* __restrict__ BFpz, const float* __restrict__ b_pz,
    const uint4* __restrict__ Wihx4, const uint4* __restrict__ BFihz,
    const uint4* __restrict__ BFhh, const float* __restrict__ b_lstm,
    float* __restrict__ g_out, float2* __restrict__ g_q2, float2* __restrict__ g_p2,
    const float* __restrict__ x, const float* __restrict__ beta_p,
    const uint4* __restrict__ BFde, const float* __restrict__ b_de,
    double* __restrict__ accum, int* __restrict__ prog)
{
  const int tid = threadIdx.x;

  if (blockIdx.x < 128) {
    // ================= producer: phase1 =================
    __shared__ __align__(16) float s_gz[5120];        // [10][512] gate pre-acts
    __shared__ __align__(16) _Float16 s_z2[16*136];   // padded rows (stride 136)
    __shared__ __align__(16) _Float16 s_zh2[16*136];
    __shared__ __align__(16) float s_gxh[512];
    __shared__ __align__(16) float s_out[128];
    __shared__ __align__(16) float s_ehmu[128];
    __shared__ __align__(16) float s_mup[128];
    __shared__ __align__(16) float s_sgp[128];
    __shared__ __align__(16) float s_sgq[128];
    __shared__ __align__(16) unsigned s_out2[64];
    __shared__ __align__(16) unsigned s_xh2[64];
    __shared__ __align__(16) _Float16 s_h2[2][128];   // double-buffered h

    const int b = blockIdx.x;
    const int wv = tid >> 6;
    const int lane = tid & 63;
    const int l15 = lane & 15;
    const int quad = lane >> 4;

    if (tid < 128) { s_out[tid] = 0.f; s_h2[0][tid] = (_Float16)0.f; }
    if (tid < 64) s_out2[tid] = 0u;
    float c_reg = 0.f;                       // lanes<16: cell state for h-idx 16*wv+lane
    const float blst = b_lstm[tid];
    const float bias_pe = (tid < 256) ? b_pr[tid] : b_en[tid - 256];
    const float bz = b_pz[16 * wv + l15];

    // VGPR-resident MFMA B-frags (stable across the whole sequence)
    uint4 whhf[16], bfpz[4];
    #pragma unroll
    for (int i = 0; i < 16; ++i) whhf[i] = BFhh[(wv * 16 + i) * 64 + lane];
    #pragma unroll
    for (int ks = 0; ks < 4; ++ks) bfpz[ks] = BFpz[(wv * 4 + ks) * 64 + lane];

    // t=0 xhat into LDS, then one full barrier before the loop
    if (tid >= 192 && tid < 256) s_xh2[tid - 192] = xhat2g[(size_t)b * 64 + (tid - 192)];
    __syncthreads();

    for (int t = 0; t < TT; ++t) {
      const size_t pb = (size_t)t * BB + b;
      const float* epsb = eps + pb * 1280;
      float e0 = epsb[tid];
      float e1 = epsb[tid + 512];
      float e2 = (tid < 256) ? epsb[tid + 1024] : 0.f;
      unsigned xh_next = 0;
      if (t + 1 < TT && tid >= 192 && tid < 256)
        xh_next = xhat2g[(pb + BB) * 64 + (tid - 192)];

      // prior (tid<256) / encoder (tid>=256): fdot2, weights streamed from L2.
      // s_out2/s_out/s_h2/s_xh2 ordered by prev timestep's final raw barrier.
      {
        float4 a4 = {bias_pe, 0.f, 0.f, 0.f};
        if (tid < 256) {
          #pragma unroll 4
          for (int k8 = 0; k8 < 16; ++k8) {
            uint4 w = Wpr4[k8 * 256 + tid];
            uint4 o = *(const uint4*)&s_out2[k8 * 4];
            dotacc4(w, o, a4);
          }
          float ph = fmaxf(hsum4(a4), 0.f);
          if (tid < 128) s_mup[tid] = ph;
          else {
            float y = __expf(ph) + 0.5f;
            float sp = (y > 20.f) ? y : __logf(1.f + __expf(y));
            s_sgp[tid - 128] = sp;
          }
        } else {
          int j2 = tid - 256;
          #pragma unroll 4
          for (int k8 = 0; k8 < 16; ++k8) {
            uint4 w = Wen4[k8 * 256 + j2];
            uint4 o = *(const uint4*)&s_out2[k8 * 4];
            dotacc4(w, o, a4);
          }
          #pragma unroll 4
          for (int k8 = 16; k8 < 32; ++k8) {
            uint4 w = Wen4[k8 * 256 + j2];
            uint4 o = *(const uint4*)&s_xh2[(k8 - 16) * 4];
            dotacc4(w, o, a4);
          }
          float eh = fmaxf(hsum4(a4), 0.f);
          if (j2 < 128) s_ehmu[j2] = eh;
          else s_sgq[j2 - 128] = __expf(eh);
        }
      }
      bar_lds();                             // B2

      // z into padded s_z2 rows (sample = row)
      {
        int l = tid & 127, s0 = tid >> 7;
        float mu = s_ehmu[l] + s_mup[l];
        float sq = s_sgq[l];
        s_z2[s0 * 136 + l]        = (_Float16)(mu + sq * e0);
        s_z2[(s0 + 4) * 136 + l]  = (_Float16)(mu + sq * e1);
        if (tid < 256) s_z2[(s0 + 8) * 136 + l] = (_Float16)(mu + sq * e2);
      }
      bar_lds();                             // B3

      // batched sc1 publication of timestep t; latency hides under z_hat /
      // gates-x / gates-z; drained at B5's full __syncthreads.
      if (tid < 128) {
        gstore2(&g_q2[pb * 128 + tid], s_ehmu[tid] + s_mup[tid], s_sgq[tid]);
      } else if (tid < 256) {
        gstore(&g_out[pb * 128 + tid - 128], s_out[tid - 128]);
      } else if (tid < 384) {
        int l = tid - 256;
        gstore2(&g_p2[pb * 128 + l], s_mup[l], s_sgp[l]);
      }

      // z_hat via MFMA: wave wv -> cols [16wv,16wv+16), rows = samples
      {
        uint4 a[4];
        #pragma unroll
        for (int ks = 0; ks < 4; ++ks)
          a[ks] = *(const uint4*)&s_z2[l15 * 136 + ks * 32 + quad * 8];
        f32x4 acc = {bz, bz, bz, bz};
        #pragma unroll
        for (int ks = 0; ks < 4; ++ks)
          acc = mfma16(a[ks], bfpz[ks], acc);
        #pragma unroll
        for (int r = 0; r < 4; ++r) {
          int s = quad * 4 + r;
          if (s < 10)
            s_zh2[s * 136 + 16 * wv + l15] = (_Float16)fmaxf(acc[r], 0.f);
        }
      }
      // gates-x: fdot2, row tid, result to s_gxh
      {
        float4 a4 = {blst, 0.f, 0.f, 0.f};
        #pragma unroll 4
        for (int k8 = 0; k8 < 16; ++k8) {
          uint4 w = Wihx4[k8 * 512 + tid];
          uint4 xv = *(const uint4*)&s_xh2[k8 * 4];
          dotacc4(w, xv, a4);
        }
        s_gxh[tid] = hsum4(a4);
      }
      bar_lds();                             // B4

      // gates-z via MFMA: wave wv, nt=gate, cols 128*nt + 16*wv + l15
      {
        uint4 a[4];
        #pragma unroll
        for (int ks = 0; ks < 4; ++ks)
          a[ks] = *(const uint4*)&s_zh2[l15 * 136 + ks * 32 + quad * 8];
        #pragma unroll
        for (int nt = 0; nt < 4; ++nt) {
          float gx = s_gxh[128 * nt + 16 * wv + l15];
          f32x4 acc = {gx, gx, gx, gx};
          #pragma unroll
          for (int ks = 0; ks < 4; ++ks)
            acc = mfma16(a[ks], BFihz[((wv * 4 + nt) * 4 + ks) * 64 + lane], acc);
          #pragma unroll
          for (int r = 0; r < 4; ++r) {
            int s = quad * 4 + r;
            if (s < 10)
              s_gz[s * 512 + 128 * nt + 16 * wv + l15] = acc[r];
          }
        }
      }
      __syncthreads();                       // B5 FULL: drains g_* sc1 stores + orders s_gz

      // publish progress: timestep t's g_* arrays are device-visible now
      if (tid == 0)
        __hip_atomic_store(&prog[b], t + 1, __ATOMIC_RELAXED, __HIP_MEMORY_SCOPE_AGENT);

      // serial LSTM over 10 samples, double-buffered h, raw barriers only.
      float oacc = 0.f;
      for (int s = 0; s < 10; ++s) {
        const _Float16* hb = s_h2[s & 1];
        uint4 a[4];
        #pragma unroll
        for (int ks = 0; ks < 4; ++ks)
          a[ks] = *(const uint4*)&hb[ks * 32 + quad * 8];
        f32x4 acc[4];
        #pragma unroll
        for (int nt = 0; nt < 4; ++nt) {
          float cz = s_gz[s * 512 + 128 * nt + 16 * wv + l15];
          acc[nt] = f32x4{cz, cz, cz, cz};
        }
        #pragma unroll
        for (int nt = 0; nt < 4; ++nt)
          #pragma unroll
          for (int ks = 0; ks < 4; ++ks)
            acc[nt] = mfma16(a[ks], whhf[nt * 4 + ks], acc[nt]);
        if (lane < 16) {
          float gi = acc[0][0], gf = acc[1][0], gg = acc[2][0], go = acc[3][0];
          c_reg = fsigm(gf) * c_reg + fsigm(gi) * ftanh(gg);
          float h = fsigm(go) * ftanh(c_reg);
          oacc += h;
          s_h2[(s + 1) & 1][16 * wv + lane] = (_Float16)h;
        }
        if (s < 9) bar_lds();
      }
      // epilogue: out / out2 / next-t xhat, then ONE raw barrier covers all
      if (lane < 16) {
        float v = oacc * 0.1f;
        s_out[16 * wv + lane] = v;
        float vn = __shfl_xor(v, 1, 64);
        if (!(lane & 1)) s_out2[8 * wv + (lane >> 1)] = packf16(v, vn);
      }
      if (t + 1 < TT && tid >= 192 && tid < 256) s_xh2[tid - 192] = xh_next;
      bar_lds();
    }
  } else {
    // ================= consumer: phase2, MFMA + swizzled LDS =================
    __shared__ __align__(16) _Float16 c_z2[48 * 128];   // z rows (40 + 8 pad), swizzled
    __shared__ __align__(16) _Float16 c_a2[48 * 256];   // [z_hat | out] GEMM A, swizzled
    __shared__ __align__(16) float c_x[4 * 800];
    __shared__ __align__(16) unsigned c_out2[256];
    __shared__ __align__(16) float c_muq[512], c_sgq[512], c_mup[512], c_sgp[512];
    __shared__ float c_wred[8];

    const int cid = blockIdx.x - 128;
    const int wv = tid >> 6;
    const int lane = tid & 63;
    const int l15 = lane & 15;
    const int quad = lane >> 4;
    const float beta = beta_p[0];

    for (int c = cid; c < 3072; c += 128) {
      const int p0 = c * 4;            // 4 pairs, all same timestep
      const int t = p0 >> 7;
      const int b0 = p0 & 127;

      if (tid < 4) {
        while (__hip_atomic_load(&prog[b0 + tid], __ATOMIC_RELAXED,
                                 __HIP_MEMORY_SCOPE_AGENT) <= t)
          __builtin_amdgcn_s_sleep(8);
      }
      __syncthreads();                 // flags seen; also guards LDS reuse

      float acc_loc = 0.f;
      {
        size_t gi = (size_t)p0 * 128 + tid;
        float2 q = gload2(&g_q2[gi]); c_muq[tid] = q.x; c_sgq[tid] = q.y;
        float2 pv = gload2(&g_p2[gi]); c_mup[tid] = pv.x; c_sgp[tid] = pv.y;
      }
      if (tid < 256) {
        int pair = tid >> 6, m = tid & 63;
        const float* o = g_out + (size_t)p0 * 128 + pair * 128;
        c_out2[tid] = packf16(gload(o + 2*m), gload(o + 2*m + 1));
      }
      // stage x rows for the 4 pairs
      for (int i = tid; i < 3200; i += 512) {
        int pp = i / 800;
        int d = i - pp * 800;
        int p = p0 + pp, bb = p & 127, tt2 = p >> 7;
        c_x[i] = x[((size_t)bb * TT + tt2) * 800 + d];
      }
      __syncthreads();

      // z + KL: one (pp,l) per thread
      {
        int l = tid & 127, pp = tid >> 7;
        float mq = c_muq[pp*128 + l], sq = c_sgq[pp*128 + l];
        float mp = c_mup[pp*128 + l], spv = c_sgp[pp*128 + l];
        float inv_sp = frcp(spv);
        float lsq = __logf(sq), lsp = __logf(spv);
        const float* ep = eps + (size_t)(p0 + pp) * 1280 + l;
        float kl = 0.f;
        #pragma unroll
        for (int s = 0; s < 10; ++s) {
          float e = ep[s * 128];
          float z = mq + sq * e;
          c_z2[swz128(pp * 10 + s, l)] = (_Float16)z;
          float ap = (z - mp) * inv_sp;
          kl += (-0.5f * e * e - lsq) - (-0.5f * ap * ap - lsp);
        }
        acc_loc -= beta * kl;
      }
      // out half of A: rows 0..39 get out[pp] in cols 128..255 (u32 pairs, swizzled)
      for (int i = tid; i < 2560; i += 512) {
        int r = i >> 6, m = i & 63;
        int pp = (r * 205) >> 11;      // r/10 for r<48
        ((unsigned*)c_a2)[r * 128 + 64 + (m ^ ((r & 7) << 2))] = c_out2[pp * 64 + m];
      }
      __syncthreads();

      // z_hat via MFMA: M=48(40 used) N=128 K=128, BFpz frags. 24 tiles / 8 waves.
      for (int tile = wv; tile < 24; tile += 8) {
        int mt = tile >> 3, nt = tile & 7;
        uint4 a[4];
        #pragma unroll
        for (int ks = 0; ks < 4; ++ks)
          a[ks] = *(const uint4*)&c_z2[swz128(mt * 16 + l15, ks * 32 + quad * 8)];
        float bzt = b_pz[16 * nt + l15];
        f32x4 acc = {bzt, bzt, bzt, bzt};
        #pragma unroll
        for (int ks = 0; ks < 4; ++ks)
          acc = mfma16(a[ks], BFpz[(nt * 4 + ks) * 64 + lane], acc);
        #pragma unroll
        for (int r = 0; r < 4; ++r) {
          int row = mt * 16 + quad * 4 + r;
          c_a2[swz256(row, 16 * nt + l15)] = (_Float16)fmaxf(acc[r], 0.f);
        }
      }
      __syncthreads();

      // decoder GEMM: M=48(40 used) N=800 K=256 + Bernoulli epilogue
      #pragma unroll
      for (int mt = 0; mt < 3; ++mt) {
        uint4 a[8];
        #pragma unroll
        for (int ks = 0; ks < 8; ++ks)
          a[ks] = *(const uint4*)&c_a2[swz256(mt * 16 + l15, ks * 32 + quad * 8)];
        for (int nt = wv; nt < 50; nt += 8) {
          f32x4 acc = {0.f, 0.f, 0.f, 0.f};
          #pragma unroll
          for (int ks = 0; ks < 8; ++ks)
            acc = mfma16(a[ks], BFde[(nt * 8 + ks) * 64 + lane], acc);
          int d = 16 * nt + l15;
          float bd = b_de[d];
          #pragma unroll
          for (int r = 0; r < 4; ++r) {
            int row = mt * 16 + quad * 4 + r;
            if (row < 40) {
              int pp = (row * 205) >> 11;
              float lg = fmaxf(acc[r] + bd, 0.f);
              float xd = c_x[pp * 800 + d];
              acc_loc += xd * lg - lg - __logf(1.f + __expf(-lg));
            }
          }
        }
      }

      float v = acc_loc;
      #pragma unroll
      for (int off = 32; off > 0; off >>= 1) v += __shfl_down(v, off, 64);
      if ((tid & 63) == 0) c_wred[tid >> 6] = v;
      __syncthreads();
      if (tid == 0) {
        double tot = 0.0;
        #pragma unroll
        for (int w = 0; w < 8; ++w) tot += (double)c_wred[w];
        atomicAdd(accum, tot);
      }
      __syncthreads();                 // c_wred / LDS safe for next chunk
    }
  }
}

__global__ void finalize_kernel(const double* __restrict__ accum, float* __restrict__ out) {
  if (threadIdx.x == 0 && blockIdx.x == 0)
    out[0] = (float)(-accum[0] / 122880.0);   // B*T*S
}

// ---------------- host ----------------
extern "C" void kernel_launch(void* const* d_in, const int* in_sizes, int n_in,
                              void* d_out, int out_size, void* d_ws, size_t ws_size,
                              hipStream_t stream) {
  const float* x    = (const float*)d_in[0];
  const float* beta = (const float*)d_in[1];
  const float* eps  = (const float*)d_in[2];
  const float* W_px = (const float*)d_in[3];
  const float* b_px = (const float*)d_in[4];
  const float* W_pz = (const float*)d_in[5];
  const float* b_pz = (const float*)d_in[6];
  const float* W_pr = (const float*)d_in[7];
  const float* b_pr = (const float*)d_in[8];
  const float* W_en = (const float*)d_in[9];
  const float* b_en = (const float*)d_in[10];
  const float* W_de = (const float*)d_in[11];
  const float* b_de = (const float*)d_in[12];
  const float* W_ih = (const float*)d_in[13];
  const float* W_hh = (const float*)d_in[14];
  const float* b_ih = (const float*)d_in[15];
  const float* b_hh = (const float*)d_in[16];
  float* ws = (float*)d_ws;

  prep_misc<<<dim3(1), dim3(512), 0, stream>>>(b_ih, b_hh, ws + O_BL,
                                               (double*)(ws + O_ACC), (int*)(ws + O_PROG));

  auto pk = [&](const float* src, size_t off, int J, int rs, int k0, int K) {
    int total = J * (K / 2);
    prep_pack_f16<<<dim3((total + 255) / 256), dim3(256), 0, stream>>>(
        src, (unsigned*)(ws + off), J, rs, k0, total);
  };
  pk(W_pr, O_WPR, 256, 128, 0, 128);
  pk(W_en, O_WEN, 256, 256, 0, 256);
  pk(W_ih, O_WIHX, 512, 256, 0, 128);
  // MFMA B-frag packs
  prep_bfrag<<<dim3(128), dim3(256), 0, stream>>>(W_ih, (unsigned*)(ws + O_BFIZ), 256, 128, 4, 0, 32768);
  prep_bfrag<<<dim3(128), dim3(256), 0, stream>>>(W_hh, (unsigned*)(ws + O_BFHH), 128, 0, 4, 0, 32768);
  prep_bfrag<<<dim3(32),  dim3(256), 0, stream>>>(W_pz, (unsigned*)(ws + O_BFPZ), 128, 0, 4, 1, 8192);
  prep_bfrag<<<dim3(400), dim3(256), 0, stream>>>(W_de, (unsigned*)(ws + O_BFDE), 256, 0, 8, 1, 102400);
  prep_transpose<<<dim3((102400 + 255) / 256), dim3(256), 0, stream>>>(
      W_px, ws + O_WPX, 128, 800, 0, 102400);

  xhat_kernel<<<dim3(1536), dim3(256), 0, stream>>>(x, ws + O_WPX, b_px, (unsigned*)(ws + O_XHAT));

  // fused cooperative producer/consumer launch
  {
    const unsigned* xhat2g = (const unsigned*)(ws + O_XHAT);
    const uint4* Wpr4  = (const uint4*)(ws + O_WPR);
    const uint4* Wen4  = (const uint4*)(ws + O_WEN);
    const uint4* BFpz  = (const uint4*)(ws + O_BFPZ);
    const uint4* Wihx4 = (const uint4*)(ws + O_WIHX);
    const uint4* BFihz = (const uint4*)(ws + O_BFIZ);
    const uint4* BFhh  = (const uint4*)(ws + O_BFHH);
    const uint4* BFde  = (const uint4*)(ws + O_BFDE);
    const float* b_lstm = ws + O_BL;
    float* g_out = ws + O_OUT;
    float2* g_q2 = (float2*)(ws + O_Q2);
    float2* g_p2 = (float2*)(ws + O_P2);
    double* accum = (double*)(ws + O_ACC);
    int* prog = (int*)(ws + O_PROG);

    void* kargs[] = {
      (void*)&eps, (void*)&xhat2g,
      (void*)&Wpr4, (void*)&b_pr, (void*)&Wen4, (void*)&b_en,
      (void*)&BFpz, (void*)&b_pz, (void*)&Wihx4, (void*)&BFihz,
      (void*)&BFhh, (void*)&b_lstm,
      (void*)&g_out, (void*)&g_q2, (void*)&g_p2,
      (void*)&x, (void*)&beta,
      (void*)&BFde, (void*)&b_de,
      (void*)&accum, (void*)&prog
    };
    hipLaunchCooperativeKernel((void*)fused_kernel, dim3(256), dim3(512),
                               kargs, 0, stream);
  }

  finalize_kernel<<<dim3(1), dim3(64), 0, stream>>>((const double*)(ws + O_ACC), (float*)d_out);
}